// Round 6
// baseline (320.876 us; speedup 1.0000x reference)
//
#include <hip/hip_runtime.h>
#include <hip/hip_bf16.h>
#include <math.h>

#define BB 2
#define SS 4096
#define DD 512
#define HH 8
#define HD 64
#define MSD (BB*SS*DD)          // 4194304 elements per matrix
#define WSZ (DD*DD)             // 262144 elements per weight

// ws layout (ushort elements):
//   Qb @ 0      [bh][s][hd]  (pre-scaled by log2e/sqrt(512))
//   Kb @ MSD    [bh][s][hd]
//   Vt @ 2*MSD  [bh][hd][s]
//   xb @ 4*MSD  [m][k]            (dead after qkv_mfma)
//   Wb @ 5*MSD  3 x [n][k]        (dead after qkv_mfma)
//   Opart @ 3*MSD (as f32): 512 x 128 x 64 f32 = 16.78MB, overlays [3*MSD,5*MSD)
//   Lpart @ 5*MSD (as f32): 512 x 128 f32, overlays Wb
#define XOFF (4*(size_t)MSD)
#define WOFF (5*(size_t)MSD)
#define POFF (3*(size_t)MSD)

typedef __attribute__((ext_vector_type(8))) short bf16x8;
typedef __attribute__((ext_vector_type(4))) float f32x4;

__device__ __forceinline__ unsigned short f2bf(float f) {
    unsigned int u = __float_as_uint(f);
    u += 0x7fff + ((u >> 16) & 1);
    return (unsigned short)(u >> 16);
}
__device__ __forceinline__ unsigned int pk2bf(float a, float b) {
    __hip_bfloat162 h = __float22bfloat162_rn(make_float2(a, b));
    union { __hip_bfloat162 h2; unsigned int u; } cv; cv.h2 = h;
    return cv.u;   // low 16 = a, high 16 = b
}

#define GLD16(gsrc, ldst) \
    __builtin_amdgcn_global_load_lds((const __attribute__((address_space(1))) unsigned int*)(gsrc), \
                                     (__attribute__((address_space(3))) unsigned int*)(ldst), 16, 0, 0)

// ---------------------------------------------------------------------------
// Balanced schedule: per bh, 48 chunks packed into 16 triples summing to 66.
// Block bx = k*256 + ti*16 + bh: {j, j+256, j+512} share a CU.
// ---------------------------------------------------------------------------
#define CH(qb,t0,t1) ((unsigned)(qb) | ((unsigned)(t0)<<8) | ((unsigned)(t1)<<16))
__device__ __constant__ unsigned int SCHED[48] = {
  CH(31,0,32),  CH(31,32,64), CH(0,0,2),     // 32+32+2
  CH(15,0,32),  CH(29,0,30),  CH(1,0,4),     // 32+30+4
  CH(29,30,60), CH(14,0,30),  CH(2,0,6),     // 30+30+6
  CH(28,0,29),  CH(28,29,58), CH(3,0,8),     // 29+29+8
  CH(27,0,28),  CH(13,0,28),  CH(4,0,10),    // 28+28+10
  CH(26,0,27),  CH(26,27,54), CH(5,0,12),    // 27+27+12
  CH(25,0,26),  CH(12,0,26),  CH(6,0,14),    // 26+26+14
  CH(24,0,25),  CH(24,25,50), CH(7,0,16),    // 25+25+16
  CH(30,0,31),  CH(17,0,18),  CH(16,0,17),   // 31+18+17
  CH(30,31,62), CH(17,18,36), CH(16,17,34),  // 31+18+17
  CH(27,28,56), CH(19,0,20),  CH(8,0,18),    // 28+20+18
  CH(25,26,52), CH(20,0,21),  CH(18,0,19),   // 26+21+19
  CH(23,0,24),  CH(22,0,23),  CH(18,19,38),  // 24+23+19
  CH(23,24,48), CH(21,0,22),  CH(19,20,40),  // 24+22+20
  CH(11,0,24),  CH(21,22,44), CH(9,0,20),    // 24+22+20
  CH(22,23,46), CH(10,0,22),  CH(20,21,42),  // 23+22+21
};

// ---------------------------------------------------------------------------
// fp32 -> bf16 convert: x (MSD els) and Wq|Wk|Wv (3*WSZ els). 8 els/thread.
// ---------------------------------------------------------------------------
__global__ __launch_bounds__(256)
void convert_bf16(const float* __restrict__ x,
                  const float* __restrict__ Wq, const float* __restrict__ Wk,
                  const float* __restrict__ Wv, unsigned short* __restrict__ ws) {
    const int i8 = blockIdx.x*256 + threadIdx.x;
    const float* src; unsigned short* dst; size_t off;
    if (i8 < MSD/8) {
        src = x; dst = ws + XOFF; off = (size_t)i8 * 8;
    } else {
        size_t o = ((size_t)i8 - MSD/8) * 8;
        int wsel = (int)(o / WSZ);
        src = (wsel == 0) ? Wq : (wsel == 1) ? Wk : Wv;
        dst = ws + WOFF + (size_t)wsel*WSZ;
        off = o % WSZ;
    }
    float4 a = *(const float4*)&src[off];
    float4 b = *(const float4*)&src[off+4];
    unsigned short r[8] = { f2bf(a.x), f2bf(a.y), f2bf(a.z), f2bf(a.w),
                            f2bf(b.x), f2bf(b.y), f2bf(b.z), f2bf(b.w) };
    *(bf16x8*)&dst[off] = *(const bf16x8*)r;
}

// ---------------------------------------------------------------------------
// QKV GEMM: C = X @ W^T + b. 128x128 tile, BK=64, 4 waves (2x2).
// A: LDS double-buffer via global_load_lds. B: direct from global/L2 with
// 1-kt register prefetch (W is 0.5MB/z -> L2-resident; no LDS staging).
// LDS = 32KB (A dbuf; reused as C-tile) -> 3 blocks/CU with grid 768.
// Fully unrolled k-loop (static buffer indices, rule-#20 safe).
// ---------------------------------------------------------------------------
__global__ __launch_bounds__(256)
void qkv_mfma(const float* __restrict__ bq, const float* __restrict__ bk,
              const float* __restrict__ bv, unsigned short* __restrict__ ws) {
    const int z = blockIdx.z;
    const unsigned short* Xb = ws + XOFF;
    const unsigned short* Wb = ws + WOFF + (size_t)z*WSZ;
    const float* bias = (z == 0) ? bq : (z == 1) ? bk : bv;
    unsigned short* dst = ws + (size_t)z*MSD;

    __shared__ __align__(16) unsigned short Sh[2*128*64];   // A dbuf (2x16KB); reused as C-tile

    const int tid  = threadIdx.x;
    const int w    = tid >> 6, l = tid & 63;
    const int quad = l >> 4,  r16 = l & 15;
    const int wy   = w >> 1,  wx  = w & 1;
    const int m0   = blockIdx.y * 128;
    const int n0   = blockIdx.x * 128;

    const int srow   = l >> 3;
    const int schunk = (l & 7) ^ srow;

    f32x4 acc[4][4];
    #pragma unroll
    for (int i = 0; i < 4; ++i)
        #pragma unroll
        for (int j = 0; j < 4; ++j) acc[i][j] = (f32x4){0.f,0.f,0.f,0.f};

    // per-lane B row base: W[n0 + wx*64 + j*16 + r16][quad*8 + ...]
    const unsigned short* wrow = Wb + (size_t)(n0 + wx*64 + r16)*DD + quad*8;

    // prologue: stage A k-tile 0 into buf 0; load B k-tile 0 into regs
    #pragma unroll
    for (int u = 0; u < 4; ++u) {
        const int r0 = w*32 + u*8;
        GLD16(&Xb[(size_t)(m0 + r0 + srow)*DD + schunk*8], &Sh[r0*64]);
    }
    bf16x8 bfr[2][4];
    #pragma unroll
    for (int kc = 0; kc < 2; ++kc)
        #pragma unroll
        for (int j = 0; j < 4; ++j)
            bfr[kc][j] = *(const bf16x8*)(wrow + (size_t)j*(16*DD) + kc*32);

    #pragma unroll
    for (int kt = 0; kt < 8; ++kt) {
        __syncthreads();                        // drains A-DMA(kt)

        bf16x8 bnx[2][4];
        if (kt + 1 < 8) {                       // issue A-DMA(kt+1); prefetch B(kt+1)
            const int k1 = (kt + 1)*64;
            const int b1 = (kt + 1) & 1;
            #pragma unroll
            for (int u = 0; u < 4; ++u) {
                const int r0 = w*32 + u*8;
                GLD16(&Xb[(size_t)(m0 + r0 + srow)*DD + k1 + schunk*8], &Sh[b1*8192 + r0*64]);
            }
            #pragma unroll
            for (int kc = 0; kc < 2; ++kc)
                #pragma unroll
                for (int j = 0; j < 4; ++j)
                    bnx[kc][j] = *(const bf16x8*)(wrow + (size_t)j*(16*DD) + kc*32 + k1);
        }

        const unsigned short* Asb = Sh + (kt & 1)*8192;
        #pragma unroll
        for (int kc = 0; kc < 2; ++kc) {
            bf16x8 a[4];
            #pragma unroll
            for (int i = 0; i < 4; ++i) {
                const int mr = wy*64 + i*16 + r16;
                a[i] = *(const bf16x8*)&Asb[mr*64 + (((kc*4+quad) ^ (mr&7))*8)];
            }
            __builtin_amdgcn_s_setprio(1);
            #pragma unroll
            for (int i = 0; i < 4; ++i)
                #pragma unroll
                for (int j = 0; j < 4; ++j) {
                    if (z == 2)
                        acc[i][j] = __builtin_amdgcn_mfma_f32_16x16x32_bf16(a[i], bfr[kc][j], acc[i][j], 0, 0, 0);
                    else
                        acc[i][j] = __builtin_amdgcn_mfma_f32_16x16x32_bf16(bfr[kc][j], a[i], acc[i][j], 0, 0, 0);
                }
            __builtin_amdgcn_s_setprio(0);
        }
        if (kt + 1 < 8) {
            #pragma unroll
            for (int kc = 0; kc < 2; ++kc)
                #pragma unroll
                for (int j = 0; j < 4; ++j)
                    bfr[kc][j] = bnx[kc][j];
        }
    }

    __syncthreads();   // k-loop LDS reads done; reuse Sh as 128x128 C-tile

    const float qscale = 0.04419417382415922f * 1.4426950408889634f; // 1/sqrt(512)*log2e
    if (z == 2) {
        #pragma unroll
        for (int j = 0; j < 4; ++j) {
            const int nloc = wx*64 + j*16 + r16;
            const float bz = bias[n0 + nloc];
            #pragma unroll
            for (int i = 0; i < 4; ++i) {
                const int chunk = wy*8 + i*2 + (quad>>1);
                const int off   = (quad & 1) * 4;
                unsigned short r4[4];
                #pragma unroll
                for (int reg = 0; reg < 4; ++reg)
                    r4[reg] = f2bf(acc[i][j][reg] + bz);
                *(uint2*)&Sh[nloc*128 + ((chunk ^ (nloc & 7))*8) + off] = *(const uint2*)r4;
            }
        }
    } else {
        #pragma unroll
        for (int j = 0; j < 4; ++j) {
            const int nbase = wx*64 + j*16 + quad*4;
            const float4 bz4 = *(const float4*)&bias[n0 + nbase];
            const int chunk = wx*8 + j*2 + (quad>>1);
            const int off   = (quad & 1) * 4;
            #pragma unroll
            for (int i = 0; i < 4; ++i) {
                const int mloc = wy*64 + i*16 + r16;
                float v0 = acc[i][j][0] + bz4.x;
                float v1 = acc[i][j][1] + bz4.y;
                float v2 = acc[i][j][2] + bz4.z;
                float v3 = acc[i][j][3] + bz4.w;
                if (z == 0) { v0 *= qscale; v1 *= qscale; v2 *= qscale; v3 *= qscale; }
                unsigned short r4[4] = { f2bf(v0), f2bf(v1), f2bf(v2), f2bf(v3) };
                *(uint2*)&Sh[mloc*128 + ((chunk ^ (mloc & 7))*8) + off] = *(const uint2*)r4;
            }
        }
    }
    __syncthreads();

    if (z == 2) {
        const int b_ = m0 >> 12, s0_ = m0 & (SS-1);
        #pragma unroll
        for (int p = 0; p < 8; ++p) {
            const int f = p*256 + tid;
            const int nrow = f >> 4;
            const int mch  = f & 15;
            bf16x8 v = *(const bf16x8*)&Sh[nrow*128 + ((mch ^ (nrow & 7))*8)];
            const int ng = n0 + nrow;
            const int h = ng >> 6, hd = ng & 63;
            *(bf16x8*)&dst[((size_t)(b_*HH + h)*HD + hd)*SS + s0_ + mch*8] = v;
        }
    } else {
        #pragma unroll
        for (int p = 0; p < 8; ++p) {
            const int f = p*256 + tid;
            const int hh  = f >> 10;
            const int rem = f & 1023;
            const int sr  = rem >> 3;
            const int ch  = rem & 7;
            bf16x8 v = *(const bf16x8*)&Sh[sr*128 + (((hh*8 + ch) ^ (sr & 7))*8)];
            const int mg = m0 + sr;
            const int b_ = mg >> 12, s_ = mg & (SS-1);
            const int hg = (n0 >> 6) + hh;
            *(bf16x8*)&dst[((size_t)(b_*HH + hg)*SS + s_)*HD + ch*8] = v;
        }
    }
}

// ---------------------------------------------------------------------------
// MFMA flash attention, KEY-SPLIT wave roles: 8 waves = 4 q-groups (g, 32 q
// each via nt=2) x 2 key-halves (s). Each wave reads only HALF of K and V
// from LDS (halves the 8x LDS read amplification), covers 2x the queries.
// End-of-chunk: s=1 waves pass (od, lacc) to s=0 partners through LDS.
// Hoisted ds_read base pointers (imm offsets; 3 v_adds per tile).
// ---------------------------------------------------------------------------
__global__ __launch_bounds__(512, 6)
void attn_mfma(unsigned short* __restrict__ ws, float* __restrict__ out) {
    const int bx = blockIdx.x;           // [0,768)
    const int k_ = bx >> 8;              // triple element 0..2
    const int j_ = bx & 255;
    const int bh = j_ & 15;
    const int ti = j_ >> 4;              // triple 0..15
    const unsigned int e = SCHED[ti*3 + k_];
    const int qb = e & 255;
    const int t0 = (e >> 8) & 255;
    const int t1 = (e >> 16) & 255;
    const int split = !(t0 == 0 && t1 == 2*qb + 2);
    const int half  = (t0 != 0);

    const int tid  = threadIdx.x;
    const int w    = tid >> 6, l = tid & 63;   // w in [0,8)
    const int quad = l >> 4,  r16 = l & 15;
    const int g    = w & 3;                    // q-group: 32 q each
    const int s    = w >> 2;                   // key-half: 32 keys each
    const int qlo  = qb*128 + g*32;
    const int tdiag = 2*qb + (g >> 1);
    const int qoff  = (g & 1)*32;              // q offset within diag tile

    const unsigned short* Qg  = ws;             // pre-scaled by log2e/sqrt(512)
    const unsigned short* Kg  = ws + (size_t)MSD;
    const unsigned short* Vtg = ws + 2*(size_t)MSD;

    // 34KB: [0,32KB) = Ks[2]|Vs[2] during loop; epilogue od/lacc exchange
    __shared__ __align__(16) unsigned char SMEM[34816];
    unsigned short* KsB = (unsigned short*)SMEM;            // [2][64*64]
    unsigned short* VsB = (unsigned short*)(SMEM + 16384);  // [2][64*64]

    const size_t kbase = (size_t)bh*SS*HD;
    const size_t vbase = (size_t)bh*HD*SS;

    // Q B-frags: lane holds Q[q = qlo+nt*16+r16][d = kc*32+quad*8+j]
    bf16x8 bqf[2][2];
    #pragma unroll
    for (int nt = 0; nt < 2; ++nt)
        #pragma unroll
        for (int kc = 0; kc < 2; ++kc)
            bqf[nt][kc] = *(const bf16x8*)&Qg[kbase + (size_t)(qlo + nt*16 + r16)*HD + kc*32 + quad*8];

    // hoisted LDS fragment pointers (element units); imm offsets do the rest
    const int x7 = r16 & 7;
    const unsigned short* pK0 = KsB + s*2048 + r16*64 + ((quad       ^ x7)*8);
    const unsigned short* pK1 = KsB + s*2048 + r16*64 + (((4+quad)   ^ x7)*8);
    const unsigned short* pV  = VsB +          r16*64 + (((s*4+quad) ^ x7)*8);

    const f32x4 ZZ = (f32x4){0.f,0.f,0.f,0.f};
    const unsigned short onep[8] = {0x3F80,0x3F80,0x3F80,0x3F80,0x3F80,0x3F80,0x3F80,0x3F80};
    const bf16x8 ones8 = *(const bf16x8*)onep;  // bf16 1.0 x8

    f32x4 od[4][2];   // O^T accum: [mtd -> d][nt -> q], wave's key-half only
    #pragma unroll
    for (int mtd = 0; mtd < 4; ++mtd)
        #pragma unroll
        for (int nt = 0; nt < 2; ++nt) od[mtd][nt] = ZZ;
    f32x4 lacc[2] = {ZZ, ZZ};

    // staging: wave w stages rows [w*8, w*8+8) of K and V^T (1 GLD16 each)
    const int sr8 = l >> 3, sc = l & 7;
    const int srow = w*8 + sr8;
    const int scol = sc ^ (srow & 7);

    // prologue: stage tile t0 into buf 0
    {
        const int jb0 = t0*64;
        GLD16(&Kg [kbase + (size_t)(jb0 + srow)*HD + scol*8], &KsB[(w*8)*64]);
        GLD16(&Vtg[vbase + (size_t)srow*SS + jb0 + scol*8],   &VsB[(w*8)*64]);
    }

    for (int t = t0; t < t1; ++t) {
        __syncthreads();                        // drains DMA(t) for all waves

        if (t + 1 < t1) {                       // issue DMA(t+1) into other buf
            const int jb1 = (t + 1)*64;
            const int b1  = (t + 1 - t0) & 1;
            GLD16(&Kg [kbase + (size_t)(jb1 + srow)*HD + scol*8], &KsB[b1*4096 + (w*8)*64]);
            GLD16(&Vtg[vbase + (size_t)srow*SS + jb1 + scol*8],   &VsB[b1*4096 + (w*8)*64]);
        }

        if (t <= tdiag) {
            const int boff = ((t - t0) & 1) * 4096;

            // ---- S^T = K Q^T for wave's key-half: keys (2s+mm)*16+quad*4+reg
            f32x4 z[2][2];
            __builtin_amdgcn_s_setprio(1);
            #pragma unroll
            for (int mm = 0; mm < 2; ++mm) {
                bf16x8 ak0 = *(const bf16x8*)(pK0 + boff + mm*1024);
                bf16x8 ak1 = *(const bf16x8*)(pK1 + boff + mm*1024);
                #pragma unroll
                for (int nt = 0; nt < 2; ++nt) {
                    z[mm][nt] = __builtin_amdgcn_mfma_f32_16x16x32_bf16(ak0, bqf[nt][0], ZZ, 0, 0, 0);
                    z[mm][nt] = __builtin_amdgcn_mfma_f32_16x16x32_bf16(ak1, bqf[nt][1], z[mm][nt], 0, 0, 0);
                }
            }
            __builtin_amdgcn_s_setprio(0);

            if (t == tdiag) {   // causal mask on the diagonal tile
                #pragma unroll
                for (int mm = 0; mm < 2; ++mm)
                    #pragma unroll
                    for (int nt = 0; nt < 2; ++nt)
                        #pragma unroll
                        for (int reg = 0; reg < 4; ++reg)
                            if ((2*s + mm)*16 + quad*4 + reg > qoff + nt*16 + r16)
                                z[mm][nt][reg] = -1e30f;
            }

            // ---- P = exp2(z), packed bf16 pairs in-register
            unsigned int X0[2][2], X1[2][2];
            #pragma unroll
            for (int mm = 0; mm < 2; ++mm)
                #pragma unroll
                for (int nt = 0; nt < 2; ++nt) {
                    X0[mm][nt] = pk2bf(__builtin_amdgcn_exp2f(z[mm][nt][0]),
                                       __builtin_amdgcn_exp2f(z[mm][nt][1]));
                    X1[mm][nt] = pk2bf(__builtin_amdgcn_exp2f(z[mm][nt][2]),
                                       __builtin_amdgcn_exp2f(z[mm][nt][3]));
                }

            // ---- cross-quad redistribution (wave's kc=s slice):
            // pf[nt] elem j = P[s*32 + quad*8 + j][q = nt*16+r16]
            bf16x8 pf[2];
            #pragma unroll
            for (int nt = 0; nt < 2; ++nt) {
                unsigned int a0 = X0[0][nt], b0 = X0[1][nt];
                unsigned int a1 = X1[0][nt], b1 = X1[1][nt];
                asm("v_permlane32_swap_b32 %0, %1" : "+v"(a0), "+v"(b0));
                asm("v_permlane16_swap_b32 %0, %1" : "+v"(a0), "+v"(b0));
                asm("v_permlane32_swap_b32 %0, %1" : "+v"(a1), "+v"(b1));
                asm("v_permlane16_swap_b32 %0, %1" : "+v"(a1), "+v"(b1));
                unsigned int wv[4] = { a0, a1, b0, b1 };
                pf[nt] = *(const bf16x8*)wv;
            }

            // ---- O^T += V^T[:, keyhalf] P^T ; l += 1^T P^T
            __builtin_amdgcn_s_setprio(1);
            lacc[0] = __builtin_amdgcn_mfma_f32_16x16x32_bf16(ones8, pf[0], lacc[0], 0, 0, 0);
            lacc[1] = __builtin_amdgcn_mfma_f32_16x16x32_bf16(ones8, pf[1], lacc[1], 0, 0, 0);
            #pragma unroll
            for (int mtd = 0; mtd < 4; ++mtd) {
                bf16x8 av = *(const bf16x8*)(pV + boff + mtd*1024);
                od[mtd][0] = __builtin_amdgcn_mfma_f32_16x16x32_bf16(av, pf[0], od[mtd][0], 0, 0, 0);
                od[mtd][1] = __builtin_amdgcn_mfma_f32_16x16x32_bf16(av, pf[1], od[mtd][1], 0, 0, 0);
            }
            __builtin_amdgcn_s_setprio(0);
        }
    }

    // ---- cross-pair reduction: s=1 hands (od, lacc) to s=0 through LDS
    __syncthreads();                  // K/V buffers dead; loop ds/DMA drained
    if (s == 1) {
        #pragma unroll
        for (int mtd = 0; mtd < 4; ++mtd)
            #pragma unroll
            for (int nt = 0; nt < 2; ++nt)
                *(f32x4*)(SMEM + (size_t)(mtd*2+nt)*4096 + (g*64 + l)*16) = od[mtd][nt];
        float2 lx; lx.x = lacc[0][0]; lx.y = lacc[1][0];
        *(float2*)(SMEM + 32768 + (g*64 + l)*8) = lx;
    }
    __syncthreads();
    if (s == 0) {
        #pragma unroll
        for (int mtd = 0; mtd < 4; ++mtd)
            #pragma unroll
            for (int nt = 0; nt < 2; ++nt) {
                f32x4 o2 = *(const f32x4*)(SMEM + (size_t)(mtd*2+nt)*4096 + (g*64 + l)*16);
                od[mtd][nt] += o2;
            }
        float2 lx = *(const float2*)(SMEM + 32768 + (g*64 + l)*8);
        lacc[0][0] += lx.x; lacc[1][0] += lx.y;

        if (split) {
            // unnormalized partial store: Opart[p][q=128][d=64] f32, Lpart[p][q]
            const int p = 2*(bh*16 + (qb - 16)) + half;
            float* Op = (float*)(ws + POFF) + (size_t)p*(128*64);
            float* Lp = (float*)(ws + WOFF) + p*128;
            #pragma unroll
            for (int nt = 0; nt < 2; ++nt) {
                const int qloc = g*32 + nt*16 + r16;
                if (quad == 0) Lp[qloc] = lacc[nt][0];
                #pragma unroll
                for (int mtd = 0; mtd < 4; ++mtd)
                    *(f32x4*)&Op[(size_t)qloc*64 + mtd*16 + quad*4] = od[mtd][nt];
            }
        } else {
            const int b_ = bh >> 3, h = bh & 7;
            #pragma unroll
            for (int nt = 0; nt < 2; ++nt) {
                const float inv = 1.0f / lacc[nt][0];
                const int q = qlo + nt*16 + r16;
                float* op = out + ((size_t)(b_*SS + q))*DD + h*HD;
                #pragma unroll
                for (int mtd = 0; mtd < 4; ++mtd) {
                    float4 tt;
                    tt.x = od[mtd][nt][0]*inv; tt.y = od[mtd][nt][1]*inv;
                    tt.z = od[mtd][nt][2]*inv; tt.w = od[mtd][nt][3]*inv;
                    *(float4*)&op[mtd*16 + quad*4] = tt;
                }
            }
        }
    }
}

// ---------------------------------------------------------------------------
// Combine: out = (O_A + O_B) / (l_A + l_B) for the 256 split rows.
// 524288 float4s -> 2048 blocks x 256 threads.
// ---------------------------------------------------------------------------
__global__ __launch_bounds__(256)
void attn_combine(const unsigned short* __restrict__ ws, float* __restrict__ out) {
    const int i  = blockIdx.x*256 + threadIdx.x;   // float4 index
    const int d4 = i & 15;
    const int q  = (i >> 4) & 127;
    const int r  = i >> 11;                        // [0,256): bh*16 + (qb-16)
    const int bh = r >> 4, qb = 16 + (r & 15);

    const float* Opart = (const float*)(ws + POFF);
    const float* Lpart = (const float*)(ws + WOFF);

    const float4 a = *(const float4*)&Opart[((size_t)(2*r)*128 + q)*64 + d4*4];
    const float4 b = *(const float4*)&Opart[((size_t)(2*r + 1)*128 + q)*64 + d4*4];
    const float lt = Lpart[(2*r)*128 + q] + Lpart[(2*r + 1)*128 + q];
    const float inv = 1.0f / lt;

    const int qg = qb*128 + q;
    const int b_ = bh >> 3, h = bh & 7;
    float4 o;
    o.x = (a.x + b.x)*inv; o.y = (a.y + b.y)*inv;
    o.z = (a.z + b.z)*inv; o.w = (a.w + b.w)*inv;
    *(float4*)&out[((size_t)(b_*SS + qg))*DD + h*HD + d4*4] = o;
}

extern "C" void kernel_launch(void* const* d_in, const int* in_sizes, int n_in,
                              void* d_out, int out_size, void* d_ws, size_t ws_size,
                              hipStream_t stream) {
    const float* x  = (const float*)d_in[0];
    const float* Wq = (const float*)d_in[1];
    const float* bq = (const float*)d_in[2];
    const float* Wk = (const float*)d_in[3];
    const float* bk = (const float*)d_in[4];
    const float* Wv = (const float*)d_in[5];
    const float* bv = (const float*)d_in[6];
    float* out = (float*)d_out;
    unsigned short* ws = (unsigned short*)d_ws;

    const int nconv = (MSD/8 + 3*WSZ/8 + 255) / 256;
    convert_bf16<<<nconv, 256, 0, stream>>>(x, Wq, Wk, Wv, ws);

    dim3 ggrid(DD/128, (BB*SS)/128, 3);           // (4, 64, 3)
    qkv_mfma<<<ggrid, 256, 0, stream>>>(bq, bk, bv, ws);

    attn_mfma<<<768, 512, 0, stream>>>(ws, out);
    attn_combine<<<2048, 256, 0, stream>>>(ws, out);
}

// Round 7
// 152.232 us; speedup vs baseline: 2.1078x; 2.1078x over previous
//
#include <hip/hip_runtime.h>
#include <hip/hip_bf16.h>
#include <math.h>

#define BB 2
#define SS 4096
#define DD 512
#define HH 8
#define HD 64
#define MSD (BB*SS*DD)          // 4194304 elements per matrix
#define WSZ (DD*DD)             // 262144 elements per weight

// ws layout (ushort elements):
//   Qb @ 0      [bh][s][hd]  (pre-scaled by log2e/sqrt(512))
//   Kb @ MSD    [bh][s][hd]
//   Vt @ 2*MSD  [bh][hd][s]
//   xb @ 4*MSD  [m][k]            (dead after qkv)
//   Wb @ 5*MSD  3 x [n][k]        (dead after qkv)
//   Opart @ 3*MSD (as f32): 512 x 128 x 64 f32 = 16.78MB, overlays [3*MSD,5*MSD)
//   Lpart @ 5*MSD (as f32): 512 x 128 f32, overlays Wb
#define XOFF (4*(size_t)MSD)
#define WOFF (5*(size_t)MSD)
#define POFF (3*(size_t)MSD)

typedef __attribute__((ext_vector_type(8))) short bf16x8;
typedef __attribute__((ext_vector_type(4))) float f32x4;

__device__ __forceinline__ unsigned short f2bf(float f) {
    unsigned int u = __float_as_uint(f);
    u += 0x7fff + ((u >> 16) & 1);
    return (unsigned short)(u >> 16);
}
__device__ __forceinline__ unsigned int pk2bf(float a, float b) {
    __hip_bfloat162 h = __float22bfloat162_rn(make_float2(a, b));
    union { __hip_bfloat162 h2; unsigned int u; } cv; cv.h2 = h;
    return cv.u;   // low 16 = a, high 16 = b
}

#define GLD16(gsrc, ldst) \
    __builtin_amdgcn_global_load_lds((const __attribute__((address_space(1))) unsigned int*)(gsrc), \
                                     (__attribute__((address_space(3))) unsigned int*)(ldst), 16, 0, 0)

// ---------------------------------------------------------------------------
// Balanced schedule: per bh, 48 chunks packed into 16 triples summing to 66.
// Block bx = k*256 + ti*16 + bh: {j, j+256, j+512} share a CU.
// ---------------------------------------------------------------------------
#define CH(qb,t0,t1) ((unsigned)(qb) | ((unsigned)(t0)<<8) | ((unsigned)(t1)<<16))
__device__ __constant__ unsigned int SCHED[48] = {
  CH(31,0,32),  CH(31,32,64), CH(0,0,2),     // 32+32+2
  CH(15,0,32),  CH(29,0,30),  CH(1,0,4),     // 32+30+4
  CH(29,30,60), CH(14,0,30),  CH(2,0,6),     // 30+30+6
  CH(28,0,29),  CH(28,29,58), CH(3,0,8),     // 29+29+8
  CH(27,0,28),  CH(13,0,28),  CH(4,0,10),    // 28+28+10
  CH(26,0,27),  CH(26,27,54), CH(5,0,12),    // 27+27+12
  CH(25,0,26),  CH(12,0,26),  CH(6,0,14),    // 26+26+14
  CH(24,0,25),  CH(24,25,50), CH(7,0,16),    // 25+25+16
  CH(30,0,31),  CH(17,0,18),  CH(16,0,17),   // 31+18+17
  CH(30,31,62), CH(17,18,36), CH(16,17,34),  // 31+18+17
  CH(27,28,56), CH(19,0,20),  CH(8,0,18),    // 28+20+18
  CH(25,26,52), CH(20,0,21),  CH(18,0,19),   // 26+21+19
  CH(23,0,24),  CH(22,0,23),  CH(18,19,38),  // 24+23+19
  CH(23,24,48), CH(21,0,22),  CH(19,20,40),  // 24+22+20
  CH(11,0,24),  CH(21,22,44), CH(9,0,20),    // 24+22+20
  CH(22,23,46), CH(10,0,22),  CH(20,21,42),  // 23+22+21
};

// ---------------------------------------------------------------------------
// fp32 -> bf16 convert: x (MSD els) and Wq|Wk|Wv (3*WSZ els). 8 els/thread.
// ---------------------------------------------------------------------------
__global__ __launch_bounds__(256)
void convert_bf16(const float* __restrict__ x,
                  const float* __restrict__ Wq, const float* __restrict__ Wk,
                  const float* __restrict__ Wv, unsigned short* __restrict__ ws) {
    const int i8 = blockIdx.x*256 + threadIdx.x;
    const float* src; unsigned short* dst; size_t off;
    if (i8 < MSD/8) {
        src = x; dst = ws + XOFF; off = (size_t)i8 * 8;
    } else {
        size_t o = ((size_t)i8 - MSD/8) * 8;
        int wsel = (int)(o / WSZ);
        src = (wsel == 0) ? Wq : (wsel == 1) ? Wk : Wv;
        dst = ws + WOFF + (size_t)wsel*WSZ;
        off = o % WSZ;
    }
    float4 a = *(const float4*)&src[off];
    float4 b = *(const float4*)&src[off+4];
    unsigned short r[8] = { f2bf(a.x), f2bf(a.y), f2bf(a.z), f2bf(a.w),
                            f2bf(b.x), f2bf(b.y), f2bf(b.z), f2bf(b.w) };
    *(bf16x8*)&dst[off] = *(const bf16x8*)r;
}

// ---------------------------------------------------------------------------
// Z-FUSED QKV GEMM: Q,K,V C-tiles computed together, sharing the A (X) tile.
// Grid (4 n, 64 m) = 256 blocks = exactly 1/CU. 512 threads = 8 waves (2m x 4n),
// wave sub-tile 64m x 32n per z. BK=64 double-buffered: A dbuf 32KB +
// 3 x B dbuf 96KB = 128KB LDS. Per kt per wave: 48 MFMAs (3z x 2kc x 4x2).
// A staged once per block (was 3x across z-blocks); no dispatch tail.
// Epilogue per z: C through LDS (reuse A region) -> coalesced stores.
// ---------------------------------------------------------------------------
__global__ __launch_bounds__(512, 2)
void qkv_fused(const float* __restrict__ bq, const float* __restrict__ bk,
               const float* __restrict__ bv, unsigned short* __restrict__ ws) {
    const unsigned short* Xb = ws + XOFF;
    const unsigned short* Wz0 = ws + WOFF;
    const unsigned short* Wz1 = ws + WOFF + WSZ;
    const unsigned short* Wz2 = ws + WOFF + 2*(size_t)WSZ;

    __shared__ __align__(16) unsigned short As[2][128*64];      // 32KB; reused as C-tile
    __shared__ __align__(16) unsigned short Bs[3][2][128*64];   // 96KB

    const int tid  = threadIdx.x;
    const int w    = tid >> 6, l = tid & 63;
    const int quad = l >> 4,  r16 = l & 15;
    const int wm   = w >> 2,  wn  = w & 3;     // 2 x 4 wave grid
    const int n0   = blockIdx.x * 128;
    const int m0   = blockIdx.y * 128;

    const int sr8 = l >> 3, sc = l & 7;

    f32x4 acc[3][4][2];
    #pragma unroll
    for (int z = 0; z < 3; ++z)
        #pragma unroll
        for (int i = 0; i < 4; ++i)
            #pragma unroll
            for (int j = 0; j < 2; ++j) acc[z][i][j] = (f32x4){0.f,0.f,0.f,0.f};

    // stage k-tile (k0) into buffer b: wave w stages rows [w*16, w*16+16)
    auto STAGE = [&](int k0, int b) {
        #pragma unroll
        for (int u = 0; u < 2; ++u) {
            const int r0  = w*16 + u*8;
            const int row = r0 + sr8;
            const int c   = sc ^ (row & 7);
            GLD16(&Xb [(size_t)(m0 + row)*DD + k0 + c*8], &As[b][r0*64]);
            GLD16(&Wz0[(size_t)(n0 + row)*DD + k0 + c*8], &Bs[0][b][r0*64]);
            GLD16(&Wz1[(size_t)(n0 + row)*DD + k0 + c*8], &Bs[1][b][r0*64]);
            GLD16(&Wz2[(size_t)(n0 + row)*DD + k0 + c*8], &Bs[2][b][r0*64]);
        }
    };

    STAGE(0, 0);    // prologue

    #pragma unroll
    for (int kt = 0; kt < 8; ++kt) {
        __syncthreads();                        // drains DMA(kt)
        if (kt + 1 < 8) STAGE((kt + 1)*64, (kt + 1) & 1);

        const int bb = kt & 1;
        #pragma unroll
        for (int kc = 0; kc < 2; ++kc) {
            bf16x8 a[4];
            #pragma unroll
            for (int i = 0; i < 4; ++i) {
                const int mr = wm*64 + i*16 + r16;
                a[i] = *(const bf16x8*)&As[bb][mr*64 + (((kc*4+quad) ^ (mr&7))*8)];
            }
            bf16x8 b0[2], b1[2], b2[2];
            #pragma unroll
            for (int j = 0; j < 2; ++j) {
                const int nr = wn*32 + j*16 + r16;
                const int sw = ((kc*4+quad) ^ (nr&7))*8;
                b0[j] = *(const bf16x8*)&Bs[0][bb][nr*64 + sw];
                b1[j] = *(const bf16x8*)&Bs[1][bb][nr*64 + sw];
                b2[j] = *(const bf16x8*)&Bs[2][bb][nr*64 + sw];
            }
            __builtin_amdgcn_s_setprio(1);
            #pragma unroll
            for (int i = 0; i < 4; ++i)
                #pragma unroll
                for (int j = 0; j < 2; ++j) {
                    // z<2: operand-swapped -> C^T regs ; z=2: natural -> C regs
                    acc[0][i][j] = __builtin_amdgcn_mfma_f32_16x16x32_bf16(b0[j], a[i], acc[0][i][j], 0, 0, 0);
                    acc[1][i][j] = __builtin_amdgcn_mfma_f32_16x16x32_bf16(b1[j], a[i], acc[1][i][j], 0, 0, 0);
                    acc[2][i][j] = __builtin_amdgcn_mfma_f32_16x16x32_bf16(a[i], b2[j], acc[2][i][j], 0, 0, 0);
                }
            __builtin_amdgcn_s_setprio(0);
        }
    }

    __syncthreads();   // k-loop LDS reads done; reuse As as 128x128 C-tile
    unsigned short* Ct = &As[0][0];
    const float qscale = 0.04419417382415922f * 1.4426950408889634f; // 1/sqrt(512)*log2e
    const float* biases[3] = { bq, bk, bv };

    #pragma unroll
    for (int z = 0; z < 3; ++z) {
        unsigned short* dst = ws + (size_t)z*MSD;
        const float* bias = biases[z];

        if (z == 2) {
            // natural C: lane holds C[m = wm*64+i*16+quad*4+reg][n = wn*32+j*16+r16]
            // store TRANSPOSED into Ct[n][m]
            #pragma unroll
            for (int j = 0; j < 2; ++j) {
                const int nloc = wn*32 + j*16 + r16;
                const float bz = bias[n0 + nloc];
                #pragma unroll
                for (int i = 0; i < 4; ++i) {
                    const int chunk = wm*8 + i*2 + (quad>>1);
                    const int off   = (quad & 1) * 4;
                    unsigned short r4[4];
                    #pragma unroll
                    for (int reg = 0; reg < 4; ++reg)
                        r4[reg] = f2bf(acc[2][i][j][reg] + bz);
                    *(uint2*)&Ct[nloc*128 + ((chunk ^ (nloc & 7))*8) + off] = *(const uint2*)r4;
                }
            }
        } else {
            // swapped C^T: lane holds C^T[n = wn*32+j*16+quad*4+reg][m = wm*64+i*16+r16]
            #pragma unroll
            for (int j = 0; j < 2; ++j) {
                const int nbase = wn*32 + j*16 + quad*4;
                const float4 bz4 = *(const float4*)&bias[n0 + nbase];
                const int chunk = wn*4 + j*2 + (quad>>1);
                const int off   = (quad & 1) * 4;
                #pragma unroll
                for (int i = 0; i < 4; ++i) {
                    const int mloc = wm*64 + i*16 + r16;
                    float v0 = acc[z][i][j][0] + bz4.x;
                    float v1 = acc[z][i][j][1] + bz4.y;
                    float v2 = acc[z][i][j][2] + bz4.z;
                    float v3 = acc[z][i][j][3] + bz4.w;
                    if (z == 0) { v0 *= qscale; v1 *= qscale; v2 *= qscale; v3 *= qscale; }
                    unsigned short r4[4] = { f2bf(v0), f2bf(v1), f2bf(v2), f2bf(v3) };
                    *(uint2*)&Ct[mloc*128 + ((chunk ^ (mloc & 7))*8) + off] = *(const uint2*)r4;
                }
            }
        }
        __syncthreads();

        // coalesced stores: consecutive lanes -> consecutive 16B chunks
        if (z == 2) {
            const int b_ = m0 >> 12, s0_ = m0 & (SS-1);
            #pragma unroll
            for (int p = 0; p < 4; ++p) {
                const int f = p*512 + tid;
                const int nrow = f >> 4;          // 0..127
                const int mch  = f & 15;          // 0..15
                bf16x8 v = *(const bf16x8*)&Ct[nrow*128 + ((mch ^ (nrow & 7))*8)];
                const int ng = n0 + nrow;
                const int h = ng >> 6, hd = ng & 63;
                *(bf16x8*)&dst[((size_t)(b_*HH + h)*HD + hd)*SS + s0_ + mch*8] = v;
            }
        } else {
            #pragma unroll
            for (int p = 0; p < 4; ++p) {
                const int f = p*512 + tid;
                const int hh  = f >> 10;          // 0..1
                const int rem = f & 1023;
                const int sr  = rem >> 3;         // 0..127
                const int ch  = rem & 7;
                bf16x8 v = *(const bf16x8*)&Ct[sr*128 + (((hh*8 + ch) ^ (sr & 7))*8)];
                const int mg = m0 + sr;
                const int b_ = mg >> 12, s_ = mg & (SS-1);
                const int hg = (n0 >> 6) + hh;
                *(bf16x8*)&dst[((size_t)(b_*HH + hg)*SS + s_)*HD + ch*8] = v;
            }
        }
        if (z < 2) __syncthreads();   // C-tile reused by next z
    }
}

// ---------------------------------------------------------------------------
// MFMA flash attention (R5-proven): 8 waves x 16 q each (512 threads),
// balanced triple schedule (768 blocks = 3/CU). In-register P redistribution
// via permlane32/16_swap (no Ps LDS, 0 bank conflicts, LDS 32KB, VGPR 36).
// Split rows (qb>=16, 2-way) store partial (O,l) to ws; combine sums.
// ---------------------------------------------------------------------------
__global__ __launch_bounds__(512, 6)
void attn_mfma(unsigned short* __restrict__ ws, float* __restrict__ out) {
    const int bx = blockIdx.x;           // [0,768)
    const int k_ = bx >> 8;              // triple element 0..2
    const int j_ = bx & 255;
    const int bh = j_ & 15;
    const int ti = j_ >> 4;              // triple 0..15
    const unsigned int e = SCHED[ti*3 + k_];
    const int qb = e & 255;
    const int t0 = (e >> 8) & 255;
    const int t1 = (e >> 16) & 255;
    const int split = !(t0 == 0 && t1 == 2*qb + 2);
    const int half  = (t0 != 0);

    const int tid  = threadIdx.x;
    const int w    = tid >> 6, l = tid & 63;   // w in [0,8)
    const int quad = l >> 4,  r16 = l & 15;
    const int qlo  = qb*128 + w*16;
    const int tdiag = 2*qb + (w >> 2);
    const int qoff  = (w & 3)*16;

    const unsigned short* Qg  = ws;             // pre-scaled by log2e/sqrt(512)
    const unsigned short* Kg  = ws + (size_t)MSD;
    const unsigned short* Vtg = ws + 2*(size_t)MSD;

    __shared__ __align__(16) unsigned short Ks[2][64*64];
    __shared__ __align__(16) unsigned short Vs[2][64*64];

    const size_t kbase = (size_t)bh*SS*HD;
    const size_t vbase = (size_t)bh*HD*SS;

    // Q B-frags: lane holds Q[q = qlo+r16][d = kc*32+quad*8+j]
    bf16x8 bqf[2];
    #pragma unroll
    for (int kc = 0; kc < 2; ++kc)
        bqf[kc] = *(const bf16x8*)&Qg[kbase + (size_t)(qlo + r16)*HD + kc*32 + quad*8];

    const f32x4 ZZ = (f32x4){0.f,0.f,0.f,0.f};  // persistent zero C-in
    const unsigned short onep[8] = {0x3F80,0x3F80,0x3F80,0x3F80,0x3F80,0x3F80,0x3F80,0x3F80};
    const bf16x8 ones8 = *(const bf16x8*)onep;  // bf16 1.0 x8

    f32x4 od[4];      // O^T accum: [mt -> d], q = qlo + r16
    #pragma unroll
    for (int mt = 0; mt < 4; ++mt) od[mt] = ZZ;
    f32x4 lacc = ZZ;  // D[m][q] = sum_k P[k][q], all rows equal

    // staging: wave w stages rows [w*8, w*8+8) of K and V^T (1 GLD16 each)
    const int sr8 = l >> 3, sc = l & 7;
    const int srow = w*8 + sr8;
    const int scol = sc ^ (srow & 7);

    // prologue: stage tile t0 into buf 0
    {
        const int jb0 = t0*64;
        GLD16(&Kg [kbase + (size_t)(jb0 + srow)*HD + scol*8], &Ks[0][(w*8)*64]);
        GLD16(&Vtg[vbase + (size_t)srow*SS + jb0 + scol*8],   &Vs[0][(w*8)*64]);
    }

    for (int t = t0; t < t1; ++t) {
        __syncthreads();                        // drains DMA(t) for all waves

        if (t + 1 < t1) {                       // issue DMA(t+1) into other buf
            const int jb1 = (t + 1)*64;
            const int b1  = (t + 1 - t0) & 1;
            GLD16(&Kg [kbase + (size_t)(jb1 + srow)*HD + scol*8], &Ks[b1][(w*8)*64]);
            GLD16(&Vtg[vbase + (size_t)srow*SS + jb1 + scol*8],   &Vs[b1][(w*8)*64]);
        }

        if (t <= tdiag) {
            const int bc = (t - t0) & 1;
            const unsigned short* Kb = Ks[bc];
            const unsigned short* Vb = Vs[bc];

            // ---- S^T = K Q^T : lane holds S^T[key = mt*16+quad*4+reg][q = r16]
            f32x4 z[4];
            __builtin_amdgcn_s_setprio(1);
            #pragma unroll
            for (int mt = 0; mt < 4; ++mt) {
                const int row = mt*16 + r16;
                bf16x8 ak0 = *(const bf16x8*)&Kb[row*64 + ((quad     ^ (row&7))*8)];
                bf16x8 ak1 = *(const bf16x8*)&Kb[row*64 + (((4+quad) ^ (row&7))*8)];
                z[mt] = __builtin_amdgcn_mfma_f32_16x16x32_bf16(ak0, bqf[0], ZZ, 0, 0, 0);
                z[mt] = __builtin_amdgcn_mfma_f32_16x16x32_bf16(ak1, bqf[1], z[mt], 0, 0, 0);
            }
            __builtin_amdgcn_s_setprio(0);

            if (t == tdiag) {   // causal mask on the diagonal tile
                #pragma unroll
                for (int mt = 0; mt < 4; ++mt)
                    #pragma unroll
                    for (int reg = 0; reg < 4; ++reg)
                        if (mt*16 + quad*4 + reg > qoff + r16)
                            z[mt][reg] = -1e30f;
            }

            // ---- P = exp2(z), packed bf16 pairs in-register
            unsigned int X0[4], X1[4];
            #pragma unroll
            for (int mt = 0; mt < 4; ++mt) {
                X0[mt] = pk2bf(__builtin_amdgcn_exp2f(z[mt][0]),
                               __builtin_amdgcn_exp2f(z[mt][1]));
                X1[mt] = pk2bf(__builtin_amdgcn_exp2f(z[mt][2]),
                               __builtin_amdgcn_exp2f(z[mt][3]));
            }

            // ---- cross-quad redistribution: pf[kc] elem j = P[kc*32+quad*8+j][q]
            bf16x8 pf[2];
            #pragma unroll
            for (int kc = 0; kc < 2; ++kc) {
                unsigned int a0 = X0[2*kc], b0 = X0[2*kc+1];
                unsigned int a1 = X1[2*kc], b1 = X1[2*kc+1];
                asm("v_permlane32_swap_b32 %0, %1" : "+v"(a0), "+v"(b0));
                asm("v_permlane16_swap_b32 %0, %1" : "+v"(a0), "+v"(b0));
                asm("v_permlane32_swap_b32 %0, %1" : "+v"(a1), "+v"(b1));
                asm("v_permlane16_swap_b32 %0, %1" : "+v"(a1), "+v"(b1));
                unsigned int wv[4] = { a0, a1, b0, b1 };   // w0,w1,w2,w3
                pf[kc] = *(const bf16x8*)wv;
            }

            // ---- O^T += V^T P^T ; l += 1^T P^T (ones-row MFMA)
            __builtin_amdgcn_s_setprio(1);
            lacc = __builtin_amdgcn_mfma_f32_16x16x32_bf16(ones8, pf[0], lacc, 0, 0, 0);
            lacc = __builtin_amdgcn_mfma_f32_16x16x32_bf16(ones8, pf[1], lacc, 0, 0, 0);
            #pragma unroll
            for (int mt = 0; mt < 4; ++mt) {
                const int row = mt*16 + r16;
                bf16x8 av0 = *(const bf16x8*)&Vb[row*64 + ((quad     ^ (row&7))*8)];
                bf16x8 av1 = *(const bf16x8*)&Vb[row*64 + (((4+quad) ^ (row&7))*8)];
                od[mt] = __builtin_amdgcn_mfma_f32_16x16x32_bf16(av0, pf[0], od[mt], 0, 0, 0);
                od[mt] = __builtin_amdgcn_mfma_f32_16x16x32_bf16(av1, pf[1], od[mt], 0, 0, 0);
            }
            __builtin_amdgcn_s_setprio(0);
        }
    }

    if (split) {
        // unnormalized partial store: Opart[p][q=128][d=64] f32, Lpart[p][q]
        const int p = 2*(bh*16 + (qb - 16)) + half;
        float* Op = (float*)(ws + POFF) + (size_t)p*(128*64);
        float* Lp = (float*)(ws + WOFF) + p*128;
        const int qloc = w*16 + r16;
        if (quad == 0) Lp[qloc] = lacc[0];
        #pragma unroll
        for (int mt = 0; mt < 4; ++mt)
            *(f32x4*)&Op[(size_t)qloc*64 + mt*16 + quad*4] = od[mt];
    } else {
        const int b_ = bh >> 3, h = bh & 7;
        const float inv = 1.0f / lacc[0];
        const int q = qlo + r16;
        float* op = out + ((size_t)(b_*SS + q))*DD + h*HD;
        #pragma unroll
        for (int mt = 0; mt < 4; ++mt) {
            float4 tt;
            tt.x = od[mt][0]*inv; tt.y = od[mt][1]*inv;
            tt.z = od[mt][2]*inv; tt.w = od[mt][3]*inv;
            *(float4*)&op[mt*16 + quad*4] = tt;
        }
    }
}

// ---------------------------------------------------------------------------
// Combine: out = (O_A + O_B) / (l_A + l_B) for the 256 split rows.
// 524288 float4s -> 2048 blocks x 256 threads.
// ---------------------------------------------------------------------------
__global__ __launch_bounds__(256)
void attn_combine(const unsigned short* __restrict__ ws, float* __restrict__ out) {
    const int i  = blockIdx.x*256 + threadIdx.x;   // float4 index
    const int d4 = i & 15;
    const int q  = (i >> 4) & 127;
    const int r  = i >> 11;                        // [0,256): bh*16 + (qb-16)
    const int bh = r >> 4, qb = 16 + (r & 15);

    const float* Opart = (const float*)(ws + POFF);
    const float* Lpart = (const float*)(ws + WOFF);

    const float4 a = *(const float4*)&Opart[((size_t)(2*r)*128 + q)*64 + d4*4];
    const float4 b = *(const float4*)&Opart[((size_t)(2*r + 1)*128 + q)*64 + d4*4];
    const float lt = Lpart[(2*r)*128 + q] + Lpart[(2*r + 1)*128 + q];
    const float inv = 1.0f / lt;

    const int qg = qb*128 + q;
    const int b_ = bh >> 3, h = bh & 7;
    float4 o;
    o.x = (a.x + b.x)*inv; o.y = (a.y + b.y)*inv;
    o.z = (a.z + b.z)*inv; o.w = (a.w + b.w)*inv;
    *(float4*)&out[((size_t)(b_*SS + qg))*DD + h*HD + d4*4] = o;
}

extern "C" void kernel_launch(void* const* d_in, const int* in_sizes, int n_in,
                              void* d_out, int out_size, void* d_ws, size_t ws_size,
                              hipStream_t stream) {
    const float* x  = (const float*)d_in[0];
    const float* Wq = (const float*)d_in[1];
    const float* bq = (const float*)d_in[2];
    const float* Wk = (const float*)d_in[3];
    const float* bk = (const float*)d_in[4];
    const float* Wv = (const float*)d_in[5];
    const float* bv = (const float*)d_in[6];
    float* out = (float*)d_out;
    unsigned short* ws = (unsigned short*)d_ws;

    const int nconv = (MSD/8 + 3*WSZ/8 + 255) / 256;
    convert_bf16<<<nconv, 256, 0, stream>>>(x, Wq, Wk, Wv, ws);

    dim3 ggrid(DD/128, (BB*SS)/128);              // (4, 64) = 256 blocks, 1/CU
    qkv_fused<<<ggrid, 512, 0, stream>>>(bq, bk, bv, ws);

    attn_mfma<<<768, 512, 0, stream>>>(ws, out);
    attn_combine<<<2048, 256, 0, stream>>>(ws, out);
}

// Round 8
// 151.141 us; speedup vs baseline: 2.1230x; 1.0072x over previous
//
#include <hip/hip_runtime.h>
#include <hip/hip_bf16.h>
#include <math.h>

#define BB 2
#define SS 4096
#define DD 512
#define HH 8
#define HD 64
#define MSD (BB*SS*DD)          // 4194304 elements per matrix
#define WSZ (DD*DD)             // 262144 elements per weight

// ws layout (ushort elements):
//   Qb @ 0      [bh][s][hd]  (pre-scaled by log2e/sqrt(512))
//   Kb @ MSD    [bh][s][hd]
//   Vt @ 2*MSD  [bh][hd][s]
//   xb @ 4*MSD  [m][k]            (dead after qkv)
//   Wb @ 5*MSD  3 x [n][k]        (dead after qkv)
//   Opart @ 3*MSD (as f32): 512 x 128 x 64 f32 = 16.78MB, overlays [3*MSD,5*MSD)
//   Lpart @ 5*MSD (as f32): 512 x 128 f32, overlays Wb
#define XOFF (4*(size_t)MSD)
#define WOFF (5*(size_t)MSD)
#define POFF (3*(size_t)MSD)

typedef __attribute__((ext_vector_type(8))) short bf16x8;
typedef __attribute__((ext_vector_type(4))) float f32x4;

__device__ __forceinline__ unsigned short f2bf(float f) {
    unsigned int u = __float_as_uint(f);
    u += 0x7fff + ((u >> 16) & 1);
    return (unsigned short)(u >> 16);
}
__device__ __forceinline__ unsigned int pk2bf(float a, float b) {
    __hip_bfloat162 h = __float22bfloat162_rn(make_float2(a, b));
    union { __hip_bfloat162 h2; unsigned int u; } cv; cv.h2 = h;
    return cv.u;   // low 16 = a, high 16 = b
}

#define GLD16(gsrc, ldst) \
    __builtin_amdgcn_global_load_lds((const __attribute__((address_space(1))) unsigned int*)(gsrc), \
                                     (__attribute__((address_space(3))) unsigned int*)(ldst), 16, 0, 0)

// ---------------------------------------------------------------------------
// Balanced schedule: per bh, 48 chunks packed into 16 triples summing to 66.
// Block bx = k*256 + ti*16 + bh: {j, j+256, j+512} share a CU.
// ---------------------------------------------------------------------------
#define CH(qb,t0,t1) ((unsigned)(qb) | ((unsigned)(t0)<<8) | ((unsigned)(t1)<<16))
__device__ __constant__ unsigned int SCHED[48] = {
  CH(31,0,32),  CH(31,32,64), CH(0,0,2),     // 32+32+2
  CH(15,0,32),  CH(29,0,30),  CH(1,0,4),     // 32+30+4
  CH(29,30,60), CH(14,0,30),  CH(2,0,6),     // 30+30+6
  CH(28,0,29),  CH(28,29,58), CH(3,0,8),     // 29+29+8
  CH(27,0,28),  CH(13,0,28),  CH(4,0,10),    // 28+28+10
  CH(26,0,27),  CH(26,27,54), CH(5,0,12),    // 27+27+12
  CH(25,0,26),  CH(12,0,26),  CH(6,0,14),    // 26+26+14
  CH(24,0,25),  CH(24,25,50), CH(7,0,16),    // 25+25+16
  CH(30,0,31),  CH(17,0,18),  CH(16,0,17),   // 31+18+17
  CH(30,31,62), CH(17,18,36), CH(16,17,34),  // 31+18+17
  CH(27,28,56), CH(19,0,20),  CH(8,0,18),    // 28+20+18
  CH(25,26,52), CH(20,0,21),  CH(18,0,19),   // 26+21+19
  CH(23,0,24),  CH(22,0,23),  CH(18,19,38),  // 24+23+19
  CH(23,24,48), CH(21,0,22),  CH(19,20,40),  // 24+22+20
  CH(11,0,24),  CH(21,22,44), CH(9,0,20),    // 24+22+20
  CH(22,23,46), CH(10,0,22),  CH(20,21,42),  // 23+22+21
};

// ---------------------------------------------------------------------------
// fp32 -> bf16 convert: x (MSD els) and Wq|Wk|Wv (3*WSZ els). 8 els/thread.
// ---------------------------------------------------------------------------
__global__ __launch_bounds__(256)
void convert_bf16(const float* __restrict__ x,
                  const float* __restrict__ Wq, const float* __restrict__ Wk,
                  const float* __restrict__ Wv, unsigned short* __restrict__ ws) {
    const int i8 = blockIdx.x*256 + threadIdx.x;
    const float* src; unsigned short* dst; size_t off;
    if (i8 < MSD/8) {
        src = x; dst = ws + XOFF; off = (size_t)i8 * 8;
    } else {
        size_t o = ((size_t)i8 - MSD/8) * 8;
        int wsel = (int)(o / WSZ);
        src = (wsel == 0) ? Wq : (wsel == 1) ? Wk : Wv;
        dst = ws + WOFF + (size_t)wsel*WSZ;
        off = o % WSZ;
    }
    float4 a = *(const float4*)&src[off];
    float4 b = *(const float4*)&src[off+4];
    unsigned short r[8] = { f2bf(a.x), f2bf(a.y), f2bf(a.z), f2bf(a.w),
                            f2bf(b.x), f2bf(b.y), f2bf(b.z), f2bf(b.w) };
    *(bf16x8*)&dst[off] = *(const bf16x8*)r;
}

// ---------------------------------------------------------------------------
// Z-FUSED QKV GEMM (R7-proven): Q,K,V C-tiles computed together, sharing the
// A (X) tile. Grid (4,64) = 256 blocks = 1/CU, 512 threads (8 waves, 2m x 4n).
// ---------------------------------------------------------------------------
__global__ __launch_bounds__(512, 2)
void qkv_fused(const float* __restrict__ bq, const float* __restrict__ bk,
               const float* __restrict__ bv, unsigned short* __restrict__ ws) {
    const unsigned short* Xb = ws + XOFF;
    const unsigned short* Wz0 = ws + WOFF;
    const unsigned short* Wz1 = ws + WOFF + WSZ;
    const unsigned short* Wz2 = ws + WOFF + 2*(size_t)WSZ;

    __shared__ __align__(16) unsigned short As[2][128*64];      // 32KB; reused as C-tile
    __shared__ __align__(16) unsigned short Bs[3][2][128*64];   // 96KB

    const int tid  = threadIdx.x;
    const int w    = tid >> 6, l = tid & 63;
    const int quad = l >> 4,  r16 = l & 15;
    const int wm   = w >> 2,  wn  = w & 3;     // 2 x 4 wave grid
    const int n0   = blockIdx.x * 128;
    const int m0   = blockIdx.y * 128;

    const int sr8 = l >> 3, sc = l & 7;

    f32x4 acc[3][4][2];
    #pragma unroll
    for (int z = 0; z < 3; ++z)
        #pragma unroll
        for (int i = 0; i < 4; ++i)
            #pragma unroll
            for (int j = 0; j < 2; ++j) acc[z][i][j] = (f32x4){0.f,0.f,0.f,0.f};

    // stage k-tile (k0) into buffer b: wave w stages rows [w*16, w*16+16)
    auto STAGE = [&](int k0, int b) {
        #pragma unroll
        for (int u = 0; u < 2; ++u) {
            const int r0  = w*16 + u*8;
            const int row = r0 + sr8;
            const int c   = sc ^ (row & 7);
            GLD16(&Xb [(size_t)(m0 + row)*DD + k0 + c*8], &As[b][r0*64]);
            GLD16(&Wz0[(size_t)(n0 + row)*DD + k0 + c*8], &Bs[0][b][r0*64]);
            GLD16(&Wz1[(size_t)(n0 + row)*DD + k0 + c*8], &Bs[1][b][r0*64]);
            GLD16(&Wz2[(size_t)(n0 + row)*DD + k0 + c*8], &Bs[2][b][r0*64]);
        }
    };

    STAGE(0, 0);    // prologue

    #pragma unroll
    for (int kt = 0; kt < 8; ++kt) {
        __syncthreads();                        // drains DMA(kt)
        if (kt + 1 < 8) STAGE((kt + 1)*64, (kt + 1) & 1);

        const int bb = kt & 1;
        #pragma unroll
        for (int kc = 0; kc < 2; ++kc) {
            bf16x8 a[4];
            #pragma unroll
            for (int i = 0; i < 4; ++i) {
                const int mr = wm*64 + i*16 + r16;
                a[i] = *(const bf16x8*)&As[bb][mr*64 + (((kc*4+quad) ^ (mr&7))*8)];
            }
            bf16x8 b0[2], b1[2], b2[2];
            #pragma unroll
            for (int j = 0; j < 2; ++j) {
                const int nr = wn*32 + j*16 + r16;
                const int sw = ((kc*4+quad) ^ (nr&7))*8;
                b0[j] = *(const bf16x8*)&Bs[0][bb][nr*64 + sw];
                b1[j] = *(const bf16x8*)&Bs[1][bb][nr*64 + sw];
                b2[j] = *(const bf16x8*)&Bs[2][bb][nr*64 + sw];
            }
            __builtin_amdgcn_s_setprio(1);
            #pragma unroll
            for (int i = 0; i < 4; ++i)
                #pragma unroll
                for (int j = 0; j < 2; ++j) {
                    // z<2: operand-swapped -> C^T regs ; z=2: natural -> C regs
                    acc[0][i][j] = __builtin_amdgcn_mfma_f32_16x16x32_bf16(b0[j], a[i], acc[0][i][j], 0, 0, 0);
                    acc[1][i][j] = __builtin_amdgcn_mfma_f32_16x16x32_bf16(b1[j], a[i], acc[1][i][j], 0, 0, 0);
                    acc[2][i][j] = __builtin_amdgcn_mfma_f32_16x16x32_bf16(a[i], b2[j], acc[2][i][j], 0, 0, 0);
                }
            __builtin_amdgcn_s_setprio(0);
        }
    }

    __syncthreads();   // k-loop LDS reads done; reuse As as 128x128 C-tile
    unsigned short* Ct = &As[0][0];
    const float qscale = 0.04419417382415922f * 1.4426950408889634f; // 1/sqrt(512)*log2e
    const float* biases[3] = { bq, bk, bv };

    #pragma unroll
    for (int z = 0; z < 3; ++z) {
        unsigned short* dst = ws + (size_t)z*MSD;
        const float* bias = biases[z];

        if (z == 2) {
            #pragma unroll
            for (int j = 0; j < 2; ++j) {
                const int nloc = wn*32 + j*16 + r16;
                const float bz = bias[n0 + nloc];
                #pragma unroll
                for (int i = 0; i < 4; ++i) {
                    const int chunk = wm*8 + i*2 + (quad>>1);
                    const int off   = (quad & 1) * 4;
                    unsigned short r4[4];
                    #pragma unroll
                    for (int reg = 0; reg < 4; ++reg)
                        r4[reg] = f2bf(acc[2][i][j][reg] + bz);
                    *(uint2*)&Ct[nloc*128 + ((chunk ^ (nloc & 7))*8) + off] = *(const uint2*)r4;
                }
            }
        } else {
            #pragma unroll
            for (int j = 0; j < 2; ++j) {
                const int nbase = wn*32 + j*16 + quad*4;
                const float4 bz4 = *(const float4*)&bias[n0 + nbase];
                const int chunk = wn*4 + j*2 + (quad>>1);
                const int off   = (quad & 1) * 4;
                #pragma unroll
                for (int i = 0; i < 4; ++i) {
                    const int mloc = wm*64 + i*16 + r16;
                    float v0 = acc[z][i][j][0] + bz4.x;
                    float v1 = acc[z][i][j][1] + bz4.y;
                    float v2 = acc[z][i][j][2] + bz4.z;
                    float v3 = acc[z][i][j][3] + bz4.w;
                    if (z == 0) { v0 *= qscale; v1 *= qscale; v2 *= qscale; v3 *= qscale; }
                    unsigned short r4[4] = { f2bf(v0), f2bf(v1), f2bf(v2), f2bf(v3) };
                    *(uint2*)&Ct[mloc*128 + ((chunk ^ (mloc & 7))*8) + off] = *(const uint2*)r4;
                }
            }
        }
        __syncthreads();

        if (z == 2) {
            const int b_ = m0 >> 12, s0_ = m0 & (SS-1);
            #pragma unroll
            for (int p = 0; p < 4; ++p) {
                const int f = p*512 + tid;
                const int nrow = f >> 4;          // 0..127
                const int mch  = f & 15;          // 0..15
                bf16x8 v = *(const bf16x8*)&Ct[nrow*128 + ((mch ^ (nrow & 7))*8)];
                const int ng = n0 + nrow;
                const int h = ng >> 6, hd = ng & 63;
                *(bf16x8*)&dst[((size_t)(b_*HH + h)*HD + hd)*SS + s0_ + mch*8] = v;
            }
        } else {
            #pragma unroll
            for (int p = 0; p < 4; ++p) {
                const int f = p*512 + tid;
                const int hh  = f >> 10;          // 0..1
                const int rem = f & 1023;
                const int sr  = rem >> 3;         // 0..127
                const int ch  = rem & 7;
                bf16x8 v = *(const bf16x8*)&Ct[sr*128 + (((hh*8 + ch) ^ (sr & 7))*8)];
                const int mg = m0 + sr;
                const int b_ = mg >> 12, s_ = mg & (SS-1);
                const int hg = (n0 >> 6) + hh;
                *(bf16x8*)&dst[((size_t)(b_*HH + hg)*SS + s_)*HD + ch*8] = v;
            }
        }
        if (z < 2) __syncthreads();   // C-tile reused by next z
    }
}

// ---------------------------------------------------------------------------
// MFMA flash attention: 4 waves x 32 q each (256 threads), balanced triple
// schedule (768 blocks = 3/CU). Each wave's K/V LDS reads amortize over 2x
// queries vs the 8-wave version -> LDS read traffic per tile-visit halves
// (128KB -> 64KB). In-register P via permlane (R3-proven correctness).
// launch_bounds(256,4) -> VGPR cap 128: fits (~110 demand), NO spill.
// Split rows (qb>=16, 2-way) store partial (O,l) to ws; combine sums.
// ---------------------------------------------------------------------------
__global__ __launch_bounds__(256, 4)
void attn_mfma(unsigned short* __restrict__ ws, float* __restrict__ out) {
    const int bx = blockIdx.x;           // [0,768)
    const int k_ = bx >> 8;              // triple element 0..2
    const int j_ = bx & 255;
    const int bh = j_ & 15;
    const int ti = j_ >> 4;              // triple 0..15
    const unsigned int e = SCHED[ti*3 + k_];
    const int qb = e & 255;
    const int t0 = (e >> 8) & 255;
    const int t1 = (e >> 16) & 255;
    const int split = !(t0 == 0 && t1 == 2*qb + 2);
    const int half  = (t0 != 0);

    const int tid  = threadIdx.x;
    const int w    = tid >> 6, l = tid & 63;   // w in [0,4)
    const int quad = l >> 4,  r16 = l & 15;
    const int qlo  = qb*128 + w*32;
    const int tdiag = 2*qb + (w >> 1);
    const int qoff  = 32*(w & 1);

    const unsigned short* Qg  = ws;             // pre-scaled by log2e/sqrt(512)
    const unsigned short* Kg  = ws + (size_t)MSD;
    const unsigned short* Vtg = ws + 2*(size_t)MSD;

    __shared__ __align__(16) unsigned short Ks[2][64*64];
    __shared__ __align__(16) unsigned short Vs[2][64*64];

    const size_t kbase = (size_t)bh*SS*HD;
    const size_t vbase = (size_t)bh*HD*SS;

    // Q B-frags: lane holds Q[q = qlo+nt*16+r16][d = kc*32+quad*8+j]
    bf16x8 bqf[2][2];
    #pragma unroll
    for (int nt = 0; nt < 2; ++nt)
        #pragma unroll
        for (int kc = 0; kc < 2; ++kc)
            bqf[nt][kc] = *(const bf16x8*)&Qg[kbase + (size_t)(qlo + nt*16 + r16)*HD + kc*32 + quad*8];

    const f32x4 ZZ = (f32x4){0.f,0.f,0.f,0.f};  // persistent zero C-in
    const unsigned short onep[8] = {0x3F80,0x3F80,0x3F80,0x3F80,0x3F80,0x3F80,0x3F80,0x3F80};
    const bf16x8 ones8 = *(const bf16x8*)onep;  // bf16 1.0 x8

    f32x4 od[4][2];   // O^T accum: [mt -> d][nt -> q]
    #pragma unroll
    for (int mt = 0; mt < 4; ++mt)
        #pragma unroll
        for (int nt = 0; nt < 2; ++nt) od[mt][nt] = ZZ;
    f32x4 lacc[2] = {ZZ, ZZ};   // D[m][q] = sum_k P[k][q], all rows equal

    // staging: wave w stages rows [w*16, w*16+16) of K and V^T (2 GLD16 each)
    const int sr8 = l >> 3, sc = l & 7;

    // prologue: stage tile t0 into buf 0
    {
        const int jb0 = t0*64;
        #pragma unroll
        for (int u = 0; u < 2; ++u) {
            const int row = w*16 + u*8 + sr8;
            const int c   = sc ^ (row & 7);
            GLD16(&Kg [kbase + (size_t)(jb0 + row)*HD + c*8], &Ks[0][(w*16 + u*8)*64]);
            GLD16(&Vtg[vbase + (size_t)row*SS + jb0 + c*8],   &Vs[0][(w*16 + u*8)*64]);
        }
    }

    for (int t = t0; t < t1; ++t) {
        __syncthreads();                        // drains DMA(t) for all waves

        if (t + 1 < t1) {                       // issue DMA(t+1) into other buf
            const int jb1 = (t + 1)*64;
            const int b1  = (t + 1 - t0) & 1;
            #pragma unroll
            for (int u = 0; u < 2; ++u) {
                const int row = w*16 + u*8 + sr8;
                const int c   = sc ^ (row & 7);
                GLD16(&Kg [kbase + (size_t)(jb1 + row)*HD + c*8], &Ks[b1][(w*16 + u*8)*64]);
                GLD16(&Vtg[vbase + (size_t)row*SS + jb1 + c*8],   &Vs[b1][(w*16 + u*8)*64]);
            }
        }

        if (t <= tdiag) {
            const int bc = (t - t0) & 1;
            const unsigned short* Kb = Ks[bc];
            const unsigned short* Vb = Vs[bc];

            // ---- S^T = K Q^T : lane holds S^T[key = mt*16+quad*4+reg][q = nt*16+r16]
            f32x4 z[4][2];
            __builtin_amdgcn_s_setprio(1);
            #pragma unroll
            for (int mt = 0; mt < 4; ++mt) {
                const int row = mt*16 + r16;
                bf16x8 ak0 = *(const bf16x8*)&Kb[row*64 + ((quad     ^ (row&7))*8)];
                bf16x8 ak1 = *(const bf16x8*)&Kb[row*64 + (((4+quad) ^ (row&7))*8)];
                #pragma unroll
                for (int nt = 0; nt < 2; ++nt) {
                    z[mt][nt] = __builtin_amdgcn_mfma_f32_16x16x32_bf16(ak0, bqf[nt][0], ZZ, 0, 0, 0);
                    z[mt][nt] = __builtin_amdgcn_mfma_f32_16x16x32_bf16(ak1, bqf[nt][1], z[mt][nt], 0, 0, 0);
                }
            }
            __builtin_amdgcn_s_setprio(0);

            if (t == tdiag) {   // causal mask on the diagonal tile
                #pragma unroll
                for (int mt = 0; mt < 4; ++mt)
                    #pragma unroll
                    for (int nt = 0; nt < 2; ++nt)
                        #pragma unroll
                        for (int reg = 0; reg < 4; ++reg)
                            if (mt*16 + quad*4 + reg > qoff + nt*16 + r16)
                                z[mt][nt][reg] = -1e30f;
            }

            // ---- P = exp2(z), packed bf16 pairs in-register
            unsigned int X0[4][2], X1[4][2];
            #pragma unroll
            for (int mt = 0; mt < 4; ++mt)
                #pragma unroll
                for (int nt = 0; nt < 2; ++nt) {
                    X0[mt][nt] = pk2bf(__builtin_amdgcn_exp2f(z[mt][nt][0]),
                                       __builtin_amdgcn_exp2f(z[mt][nt][1]));
                    X1[mt][nt] = pk2bf(__builtin_amdgcn_exp2f(z[mt][nt][2]),
                                       __builtin_amdgcn_exp2f(z[mt][nt][3]));
                }

            // ---- cross-quad redistribution: pf[nt][kc] elem j = P[kc*32+quad*8+j][q]
            bf16x8 pf[2][2];
            #pragma unroll
            for (int nt = 0; nt < 2; ++nt)
                #pragma unroll
                for (int kc = 0; kc < 2; ++kc) {
                    unsigned int a0 = X0[2*kc][nt], b0 = X0[2*kc+1][nt];
                    unsigned int a1 = X1[2*kc][nt], b1 = X1[2*kc+1][nt];
                    asm("v_permlane32_swap_b32 %0, %1" : "+v"(a0), "+v"(b0));
                    asm("v_permlane16_swap_b32 %0, %1" : "+v"(a0), "+v"(b0));
                    asm("v_permlane32_swap_b32 %0, %1" : "+v"(a1), "+v"(b1));
                    asm("v_permlane16_swap_b32 %0, %1" : "+v"(a1), "+v"(b1));
                    unsigned int wv[4] = { a0, a1, b0, b1 };   // w0,w1,w2,w3
                    pf[nt][kc] = *(const bf16x8*)wv;
                }

            // ---- O^T += V^T P^T ; l += 1^T P^T (ones-row MFMA)
            __builtin_amdgcn_s_setprio(1);
            #pragma unroll
            for (int nt = 0; nt < 2; ++nt) {
                lacc[nt] = __builtin_amdgcn_mfma_f32_16x16x32_bf16(ones8, pf[nt][0], lacc[nt], 0, 0, 0);
                lacc[nt] = __builtin_amdgcn_mfma_f32_16x16x32_bf16(ones8, pf[nt][1], lacc[nt], 0, 0, 0);
            }
            #pragma unroll
            for (int mt = 0; mt < 4; ++mt) {
                const int row = mt*16 + r16;
                bf16x8 av0 = *(const bf16x8*)&Vb[row*64 + ((quad     ^ (row&7))*8)];
                bf16x8 av1 = *(const bf16x8*)&Vb[row*64 + (((4+quad) ^ (row&7))*8)];
                #pragma unroll
                for (int nt = 0; nt < 2; ++nt) {
                    od[mt][nt] = __builtin_amdgcn_mfma_f32_16x16x32_bf16(av0, pf[nt][0], od[mt][nt], 0, 0, 0);
                    od[mt][nt] = __builtin_amdgcn_mfma_f32_16x16x32_bf16(av1, pf[nt][1], od[mt][nt], 0, 0, 0);
                }
            }
            __builtin_amdgcn_s_setprio(0);
        }
    }

    if (split) {
        // unnormalized partial store: Opart[p][q=128][d=64] f32, Lpart[p][q]
        const int p = 2*(bh*16 + (qb - 16)) + half;
        float* Op = (float*)(ws + POFF) + (size_t)p*(128*64);
        float* Lp = (float*)(ws + WOFF) + p*128;
        #pragma unroll
        for (int nt = 0; nt < 2; ++nt) {
            const int qloc = w*32 + nt*16 + r16;
            if (quad == 0) Lp[qloc] = lacc[nt][0];
            #pragma unroll
            for (int mt = 0; mt < 4; ++mt)
                *(f32x4*)&Op[(size_t)qloc*64 + mt*16 + quad*4] = od[mt][nt];
        }
    } else {
        const int b_ = bh >> 3, h = bh & 7;
        #pragma unroll
        for (int nt = 0; nt < 2; ++nt) {
            const float inv = 1.0f / lacc[nt][0];
            const int q = qlo + nt*16 + r16;
            float* op = out + ((size_t)(b_*SS + q))*DD + h*HD;
            #pragma unroll
            for (int mt = 0; mt < 4; ++mt) {
                float4 tt;
                tt.x = od[mt][nt][0]*inv; tt.y = od[mt][nt][1]*inv;
                tt.z = od[mt][nt][2]*inv; tt.w = od[mt][nt][3]*inv;
                *(float4*)&op[mt*16 + quad*4] = tt;
            }
        }
    }
}

// ---------------------------------------------------------------------------
// Combine: out = (O_A + O_B) / (l_A + l_B) for the 256 split rows.
// 524288 float4s -> 2048 blocks x 256 threads.
// ---------------------------------------------------------------------------
__global__ __launch_bounds__(256)
void attn_combine(const unsigned short* __restrict__ ws, float* __restrict__ out) {
    const int i  = blockIdx.x*256 + threadIdx.x;   // float4 index
    const int d4 = i & 15;
    const int q  = (i >> 4) & 127;
    const int r  = i >> 11;                        // [0,256): bh*16 + (qb-16)
    const int bh = r >> 4, qb = 16 + (r & 15);

    const float* Opart = (const float*)(ws + POFF);
    const float* Lpart = (const float*)(ws + WOFF);

    const float4 a = *(const float4*)&Opart[((size_t)(2*r)*128 + q)*64 + d4*4];
    const float4 b = *(const float4*)&Opart[((size_t)(2*r + 1)*128 + q)*64 + d4*4];
    const float lt = Lpart[(2*r)*128 + q] + Lpart[(2*r + 1)*128 + q];
    const float inv = 1.0f / lt;

    const int qg = qb*128 + q;
    const int b_ = bh >> 3, h = bh & 7;
    float4 o;
    o.x = (a.x + b.x)*inv; o.y = (a.y + b.y)*inv;
    o.z = (a.z + b.z)*inv; o.w = (a.w + b.w)*inv;
    *(float4*)&out[((size_t)(b_*SS + qg))*DD + h*HD + d4*4] = o;
}

extern "C" void kernel_launch(void* const* d_in, const int* in_sizes, int n_in,
                              void* d_out, int out_size, void* d_ws, size_t ws_size,
                              hipStream_t stream) {
    const float* x  = (const float*)d_in[0];
    const float* Wq = (const float*)d_in[1];
    const float* bq = (const float*)d_in[2];
    const float* Wk = (const float*)d_in[3];
    const float* bk = (const float*)d_in[4];
    const float* Wv = (const float*)d_in[5];
    const float* bv = (const float*)d_in[6];
    float* out = (float*)d_out;
    unsigned short* ws = (unsigned short*)d_ws;

    const int nconv = (MSD/8 + 3*WSZ/8 + 255) / 256;
    convert_bf16<<<nconv, 256, 0, stream>>>(x, Wq, Wk, Wv, ws);

    dim3 ggrid(DD/128, (BB*SS)/128);              // (4, 64) = 256 blocks, 1/CU
    qkv_fused<<<ggrid, 512, 0, stream>>>(bq, bk, bv, ws);

    attn_mfma<<<768, 256, 0, stream>>>(ws, out);
    attn_combine<<<2048, 256, 0, stream>>>(ws, out);
}